// Round 2
// baseline (958.890 us; speedup 1.0000x reference)
//
#include <hip/hip_runtime.h>
#include <math.h>

#define NC 40962
#define NF 163842
#define EPSV 1e-5f
#define LSLOPE 0.2f

// workspace layout (bytes)
#define H_BYTES   73403904ull   // 7*NC x 64 f32   (aliased by out_pre later)
#define X_BYTES   83887104ull   // NF x 128 f32
#define Y_BYTES   41943552ull   // NF x 64 f32
#define NBLK      2561
#define P_BYTES   655616ull     // NBLK*64*4

__device__ __forceinline__ float lrelu(float v) { return v > 0.f ? v : LSLOPE * v; }

// ---------------- K1: upconv GEMM  h[7n+j][c] = x1[n] . Wup[j*64+c] + bup ----------------
__global__ __launch_bounds__(256) void k_upconv(const float* __restrict__ x1,
                                                const float* __restrict__ Wup,
                                                const float* __restrict__ bup,
                                                float* __restrict__ h) {
  __shared__ float As[128][64];
  __shared__ float Bs[128][64];
  const int t = threadIdx.x;
  const int n0 = blockIdx.x * 64;
  {
    const int n = t & 63;
    const int kq = t >> 6;
    int row = n0 + n; if (row >= NC) row = NC - 1;
    const float4* src = (const float4*)(x1 + (size_t)row * 128 + kq * 32);
#pragma unroll
    for (int u = 0; u < 8; ++u) {
      float4 g = src[u];
      int k = kq * 32 + u * 4;
      As[k+0][n] = g.x; As[k+1][n] = g.y; As[k+2][n] = g.z; As[k+3][n] = g.w;
    }
  }
  const int tx = t & 15, ty = t >> 4;
  const int tx4 = tx * 4, ty4 = ty * 4;
  for (int j = 0; j < 7; ++j) {
    __syncthreads();
    {
      const int o = t & 63;
      const int kq = t >> 6;
      const float4* src = (const float4*)(Wup + (size_t)(j * 64 + o) * 128 + kq * 32);
#pragma unroll
      for (int u = 0; u < 8; ++u) {
        float4 g = src[u];
        int k = kq * 32 + u * 4;
        Bs[k+0][o] = g.x; Bs[k+1][o] = g.y; Bs[k+2][o] = g.z; Bs[k+3][o] = g.w;
      }
    }
    __syncthreads();
    float acc[4][4];
#pragma unroll
    for (int i = 0; i < 4; ++i) { acc[i][0]=0.f; acc[i][1]=0.f; acc[i][2]=0.f; acc[i][3]=0.f; }
#pragma unroll 8
    for (int k = 0; k < 128; ++k) {
      const float4 a = *(const float4*)&As[k][ty4];
      const float4 b = *(const float4*)&Bs[k][tx4];
      acc[0][0] += a.x*b.x; acc[0][1] += a.x*b.y; acc[0][2] += a.x*b.z; acc[0][3] += a.x*b.w;
      acc[1][0] += a.y*b.x; acc[1][1] += a.y*b.y; acc[1][2] += a.y*b.z; acc[1][3] += a.y*b.w;
      acc[2][0] += a.z*b.x; acc[2][1] += a.z*b.y; acc[2][2] += a.z*b.z; acc[2][3] += a.z*b.w;
      acc[3][0] += a.w*b.x; acc[3][1] += a.w*b.y; acc[3][2] += a.w*b.z; acc[3][3] += a.w*b.w;
    }
    const float4 bb = *(const float4*)(bup + j * 64 + tx4);
#pragma unroll
    for (int i = 0; i < 4; ++i) {
      int node = n0 + ty4 + i;
      if (node < NC) {
        float4 v;
        v.x = acc[i][0] + bb.x; v.y = acc[i][1] + bb.y;
        v.z = acc[i][2] + bb.z; v.w = acc[i][3] + bb.w;
        *(float4*)(h + (size_t)(7 * node + j) * 64 + tx4) = v;
      }
    }
  }
}

// ---------------- K2: build x = concat([x1u, x2], axis=1), x1u from top/down gathers ----------
__global__ void k_build_x(const float* __restrict__ h, const float* __restrict__ x2,
                          const int* __restrict__ topi, const int* __restrict__ downi,
                          float* __restrict__ x) {
  int gid = blockIdx.x * blockDim.x + threadIdx.x;
  if (gid >= NF * 32) return;
  int n = gid >> 5;
  int q = gid & 31;          // 4-channel group of 32 over 128 channels
  float4 v;
  if (q >= 16) {
    v = *(const float4*)(x2 + (size_t)n * 64 + (q - 16) * 4);
  } else if (n < NC) {
    int r = topi[n];
    v = *(const float4*)(h + (size_t)r * 64 + q * 4);
  } else {
    int i = n - NC;
    int hi = (q >= 8) ? 1 : 0;
    int r = downi[2 * i + hi];
    // channels c=q*4..q*4+3; c'=c-32*hi; sources h[r][2c'], h[r][2c'+1]
    const float4* src = (const float4*)(h + (size_t)r * 64 + 8 * q - 64 * hi);
    float4 a = src[0], b = src[1];
    v.x = 0.5f * (a.x + a.y); v.y = 0.5f * (a.z + a.w);
    v.z = 0.5f * (b.x + b.y); v.w = 0.5f * (b.z + b.w);
  }
  *(float4*)(x + (size_t)n * 128 + q * 4) = v;
}

// ---------------- K3: conv1 GEMM with gather; y_pre + BN partial stats ----------------
__global__ __launch_bounds__(256) void k_conv1(const float* __restrict__ x,
                                               const int* __restrict__ neigh,
                                               const float* __restrict__ W1,
                                               const float* __restrict__ b1,
                                               float* __restrict__ y,
                                               float* __restrict__ psum,
                                               float* __restrict__ psq) {
  __shared__ float As[128][64];
  __shared__ float Bs[128][64];
  const int t = threadIdx.x;
  const int n0 = blockIdx.x * 64;
  const int tx = t & 15, ty = t >> 4;
  const int tx4 = tx * 4, ty4 = ty * 4;
  float acc[4][4];
#pragma unroll
  for (int i = 0; i < 4; ++i) { acc[i][0]=0.f; acc[i][1]=0.f; acc[i][2]=0.f; acc[i][3]=0.f; }
  for (int j = 0; j < 7; ++j) {
    __syncthreads();
    {
      const int n = t & 63;
      const int kq = t >> 6;
      int node = n0 + n;
      int r = (node < NF) ? neigh[7 * node + j] : 0;
      const float4* src = (const float4*)(x + (size_t)r * 128 + kq * 32);
#pragma unroll
      for (int u = 0; u < 8; ++u) {
        float4 g = src[u];
        int k = kq * 32 + u * 4;
        As[k+0][n] = g.x; As[k+1][n] = g.y; As[k+2][n] = g.z; As[k+3][n] = g.w;
      }
    }
    {
      const int o = t & 63;
      const int kq = t >> 6;
      const float4* src = (const float4*)(W1 + (size_t)o * 896 + j * 128 + kq * 32);
#pragma unroll
      for (int u = 0; u < 8; ++u) {
        float4 g = src[u];
        int k = kq * 32 + u * 4;
        Bs[k+0][o] = g.x; Bs[k+1][o] = g.y; Bs[k+2][o] = g.z; Bs[k+3][o] = g.w;
      }
    }
    __syncthreads();
#pragma unroll 8
    for (int k = 0; k < 128; ++k) {
      const float4 a = *(const float4*)&As[k][ty4];
      const float4 b = *(const float4*)&Bs[k][tx4];
      acc[0][0] += a.x*b.x; acc[0][1] += a.x*b.y; acc[0][2] += a.x*b.z; acc[0][3] += a.x*b.w;
      acc[1][0] += a.y*b.x; acc[1][1] += a.y*b.y; acc[1][2] += a.y*b.z; acc[1][3] += a.y*b.w;
      acc[2][0] += a.z*b.x; acc[2][1] += a.z*b.y; acc[2][2] += a.z*b.z; acc[2][3] += a.z*b.w;
      acc[3][0] += a.w*b.x; acc[3][1] += a.w*b.y; acc[3][2] += a.w*b.z; acc[3][3] += a.w*b.w;
    }
  }
  const float4 bb = *(const float4*)(b1 + tx4);
  float vals[4][4];
#pragma unroll
  for (int i = 0; i < 4; ++i) {
    vals[i][0] = acc[i][0] + bb.x; vals[i][1] = acc[i][1] + bb.y;
    vals[i][2] = acc[i][2] + bb.z; vals[i][3] = acc[i][3] + bb.w;
  }
#pragma unroll
  for (int i = 0; i < 4; ++i) {
    int node = n0 + ty4 + i;
    if (node < NF) {
      float4 v; v.x = vals[i][0]; v.y = vals[i][1]; v.z = vals[i][2]; v.w = vals[i][3];
      *(float4*)(y + (size_t)node * 64 + tx4) = v;
    }
  }
  // block-level BN partials (deterministic)
  float s[4] = {0.f,0.f,0.f,0.f}, q[4] = {0.f,0.f,0.f,0.f};
#pragma unroll
  for (int i = 0; i < 4; ++i) {
    int node = n0 + ty4 + i;
    if (node < NF) {
#pragma unroll
      for (int o = 0; o < 4; ++o) { s[o] += vals[i][o]; q[o] += vals[i][o] * vals[i][o]; }
    }
  }
  __syncthreads();
  float* sc = &As[0][0];
#pragma unroll
  for (int o = 0; o < 4; ++o) { sc[ty * 64 + tx4 + o] = s[o]; sc[1024 + ty * 64 + tx4 + o] = q[o]; }
  __syncthreads();
  if (t < 64) {
    float S = 0.f, Q = 0.f;
#pragma unroll
    for (int r = 0; r < 16; ++r) { S += sc[r * 64 + t]; Q += sc[1024 + r * 64 + t]; }
    psum[blockIdx.x * 64 + t] = S;
    psq [blockIdx.x * 64 + t] = Q;
  }
}

// ---------------- K4/K7: finalize BN stats -> scale/shift ----------------
__global__ __launch_bounds__(256) void k_stats(const float* __restrict__ ps,
                                               const float* __restrict__ pq,
                                               int nblk,
                                               const float* __restrict__ g,
                                               const float* __restrict__ beta,
                                               float* __restrict__ st) {
  __shared__ float sh[8][64];
  const int t = threadIdx.x;
  const int c = t & 63, r = t >> 6;
  float S = 0.f, Q = 0.f;
  for (int b = r; b < nblk; b += 4) { S += ps[b * 64 + c]; Q += pq[b * 64 + c]; }
  sh[r][c] = S; sh[4 + r][c] = Q;
  __syncthreads();
  if (t < 64) {
    float Ss = sh[0][t] + sh[1][t] + sh[2][t] + sh[3][t];
    float Qs = sh[4][t] + sh[5][t] + sh[6][t] + sh[7][t];
    float mean = Ss * (1.f / (float)NF);
    float var  = Qs * (1.f / (float)NF) - mean * mean;
    var = var < 0.f ? 0.f : var;
    float scale = g[t] * rsqrtf(var + EPSV);
    st[t] = scale;
    st[64 + t] = beta[t] - mean * scale;
  }
}

// ---------------- K6: conv2 GEMM, BN1+leaky fused into gather ----------------
__global__ __launch_bounds__(256) void k_conv2(const float* __restrict__ y,
                                               const int* __restrict__ neigh,
                                               const float* __restrict__ W2,
                                               const float* __restrict__ b2,
                                               const float* __restrict__ st1,
                                               float* __restrict__ op,
                                               float* __restrict__ psum,
                                               float* __restrict__ psq) {
  __shared__ float As[64][64];
  __shared__ float Bs[64][64];
  const int t = threadIdx.x;
  const int n0 = blockIdx.x * 64;
  const int tx = t & 15, ty = t >> 4;
  const int tx4 = tx * 4, ty4 = ty * 4;
  float acc[4][4];
#pragma unroll
  for (int i = 0; i < 4; ++i) { acc[i][0]=0.f; acc[i][1]=0.f; acc[i][2]=0.f; acc[i][3]=0.f; }
  for (int j = 0; j < 7; ++j) {
    __syncthreads();
    {
      const int n = t & 63;
      const int kq = t >> 6;       // k-span 16
      int node = n0 + n;
      int r = (node < NF) ? neigh[7 * node + j] : 0;
      const float4* src = (const float4*)(y + (size_t)r * 64 + kq * 16);
#pragma unroll
      for (int u = 0; u < 4; ++u) {
        int k = kq * 16 + u * 4;
        float4 gv = src[u];
        float4 sv = *(const float4*)(st1 + k);
        float4 hv = *(const float4*)(st1 + 64 + k);
        As[k+0][n] = lrelu(gv.x * sv.x + hv.x);
        As[k+1][n] = lrelu(gv.y * sv.y + hv.y);
        As[k+2][n] = lrelu(gv.z * sv.z + hv.z);
        As[k+3][n] = lrelu(gv.w * sv.w + hv.w);
      }
    }
    {
      const int o = t & 63;
      const int kq = t >> 6;
      const float4* src = (const float4*)(W2 + (size_t)o * 448 + j * 64 + kq * 16);
#pragma unroll
      for (int u = 0; u < 4; ++u) {
        int k = kq * 16 + u * 4;
        float4 g = src[u];
        Bs[k+0][o] = g.x; Bs[k+1][o] = g.y; Bs[k+2][o] = g.z; Bs[k+3][o] = g.w;
      }
    }
    __syncthreads();
#pragma unroll 8
    for (int k = 0; k < 64; ++k) {
      const float4 a = *(const float4*)&As[k][ty4];
      const float4 b = *(const float4*)&Bs[k][tx4];
      acc[0][0] += a.x*b.x; acc[0][1] += a.x*b.y; acc[0][2] += a.x*b.z; acc[0][3] += a.x*b.w;
      acc[1][0] += a.y*b.x; acc[1][1] += a.y*b.y; acc[1][2] += a.y*b.z; acc[1][3] += a.y*b.w;
      acc[2][0] += a.z*b.x; acc[2][1] += a.z*b.y; acc[2][2] += a.z*b.z; acc[2][3] += a.z*b.w;
      acc[3][0] += a.w*b.x; acc[3][1] += a.w*b.y; acc[3][2] += a.w*b.z; acc[3][3] += a.w*b.w;
    }
  }
  const float4 bb = *(const float4*)(b2 + tx4);
  float vals[4][4];
#pragma unroll
  for (int i = 0; i < 4; ++i) {
    vals[i][0] = acc[i][0] + bb.x; vals[i][1] = acc[i][1] + bb.y;
    vals[i][2] = acc[i][2] + bb.z; vals[i][3] = acc[i][3] + bb.w;
  }
#pragma unroll
  for (int i = 0; i < 4; ++i) {
    int node = n0 + ty4 + i;
    if (node < NF) {
      float4 v; v.x = vals[i][0]; v.y = vals[i][1]; v.z = vals[i][2]; v.w = vals[i][3];
      *(float4*)(op + (size_t)node * 64 + tx4) = v;
    }
  }
  float s[4] = {0.f,0.f,0.f,0.f}, q[4] = {0.f,0.f,0.f,0.f};
#pragma unroll
  for (int i = 0; i < 4; ++i) {
    int node = n0 + ty4 + i;
    if (node < NF) {
#pragma unroll
      for (int o = 0; o < 4; ++o) { s[o] += vals[i][o]; q[o] += vals[i][o] * vals[i][o]; }
    }
  }
  __syncthreads();
  float* sc = &As[0][0];
#pragma unroll
  for (int o = 0; o < 4; ++o) { sc[ty * 64 + tx4 + o] = s[o]; sc[1024 + ty * 64 + tx4 + o] = q[o]; }
  __syncthreads();
  if (t < 64) {
    float S = 0.f, Q = 0.f;
#pragma unroll
    for (int r = 0; r < 16; ++r) { S += sc[r * 64 + t]; Q += sc[1024 + r * 64 + t]; }
    psum[blockIdx.x * 64 + t] = S;
    psq [blockIdx.x * 64 + t] = Q;
  }
}

// ---------------- K8: apply BN2 + leaky ----------------
__global__ void k_apply(const float* __restrict__ op, const float* __restrict__ st2,
                        float* __restrict__ out) {
  int gid = blockIdx.x * blockDim.x + threadIdx.x;
  if (gid >= NF * 16) return;
  int q = gid & 15;
  float4 v  = *(const float4*)(op + (size_t)gid * 4);
  float4 s  = *(const float4*)(st2 + q * 4);
  float4 sh = *(const float4*)(st2 + 64 + q * 4);
  float4 w;
  w.x = lrelu(v.x * s.x + sh.x);
  w.y = lrelu(v.y * s.y + sh.y);
  w.z = lrelu(v.z * s.z + sh.z);
  w.w = lrelu(v.w * s.w + sh.w);
  *(float4*)(out + (size_t)gid * 4) = w;
}

extern "C" void kernel_launch(void* const* d_in, const int* in_sizes, int n_in,
                              void* d_out, int out_size, void* d_ws, size_t ws_size,
                              hipStream_t stream) {
  (void)in_sizes; (void)n_in; (void)out_size; (void)ws_size;
  const float* x1   = (const float*)d_in[0];
  const float* x2   = (const float*)d_in[1];
  const int*   topi = (const int*)d_in[2];
  const int*   downi= (const int*)d_in[3];
  const int*   neigh= (const int*)d_in[4];
  const float* Wup  = (const float*)d_in[5];
  const float* bup  = (const float*)d_in[6];
  const float* W1   = (const float*)d_in[7];
  const float* b1   = (const float*)d_in[8];
  const float* g1   = (const float*)d_in[9];
  const float* be1  = (const float*)d_in[10];
  const float* W2   = (const float*)d_in[11];
  const float* b2   = (const float*)d_in[12];
  const float* g2   = (const float*)d_in[13];
  const float* be2  = (const float*)d_in[14];
  float* out = (float*)d_out;

  char* ws = (char*)d_ws;
  float* h    = (float*)(ws);
  float* x    = (float*)(ws + H_BYTES);
  float* y    = (float*)(ws + H_BYTES + X_BYTES);
  size_t o2   = H_BYTES + X_BYTES + Y_BYTES;
  float* p1s  = (float*)(ws + o2);
  float* p1q  = (float*)(ws + o2 + P_BYTES);
  float* p2s  = (float*)(ws + o2 + 2 * P_BYTES);
  float* p2q  = (float*)(ws + o2 + 3 * P_BYTES);
  float* st1  = (float*)(ws + o2 + 4 * P_BYTES);
  float* st2  = (float*)(ws + o2 + 4 * P_BYTES + 512);
  float* op   = h;  // out_pre aliases h (h is dead after k_build_x)

  k_upconv <<<(NC + 63) / 64, 256, 0, stream>>>(x1, Wup, bup, h);
  k_build_x<<<(NF * 32 + 255) / 256, 256, 0, stream>>>(h, x2, topi, downi, x);
  k_conv1  <<<NBLK, 256, 0, stream>>>(x, neigh, W1, b1, y, p1s, p1q);
  k_stats  <<<1, 256, 0, stream>>>(p1s, p1q, NBLK, g1, be1, st1);
  k_conv2  <<<NBLK, 256, 0, stream>>>(y, neigh, W2, b2, st1, op, p2s, p2q);
  k_stats  <<<1, 256, 0, stream>>>(p2s, p2q, NBLK, g2, be2, st2);
  k_apply  <<<(NF * 16 + 255) / 256, 256, 0, stream>>>(op, st2, out);
}

// Round 3
// 363.246 us; speedup vs baseline: 2.6398x; 2.6398x over previous
//
#include <hip/hip_runtime.h>
#include <math.h>

#define NC 40962
#define NF 163842
#define EPSV 1e-5f
#define LSLOPE 0.2f
#define NBLK 1281           // ceil(NF/128)

typedef __attribute__((ext_vector_type(8))) short bf16x8;
typedef __attribute__((ext_vector_type(4))) float f32x4;
typedef unsigned short u16;

#define MFMA(a,b,c) __builtin_amdgcn_mfma_f32_16x16x32_bf16(a,b,c,0,0,0)

__device__ __forceinline__ u16 f2bf(float f){
  unsigned u = __float_as_uint(f);
  u += 0x7fffu + ((u >> 16) & 1u);
  return (u16)(u >> 16);
}
__device__ __forceinline__ float bf2f(u16 h){ return __uint_as_float(((unsigned)h) << 16); }
__device__ __forceinline__ float lrelu(float v){ return v > 0.f ? v : LSLOPE * v; }

// ---------------- convert f32 -> bf16, 8 elems/thread ----------------
__global__ void k_f2bf(const float* __restrict__ s, u16* __restrict__ d, int n8){
  int i = blockIdx.x * 256 + threadIdx.x;
  if (i >= n8) return;
  const float4* sp = (const float4*)(s + (size_t)i * 8);
  float4 a = sp[0], b = sp[1];
  bf16x8 v;
  v[0]=(short)f2bf(a.x); v[1]=(short)f2bf(a.y); v[2]=(short)f2bf(a.z); v[3]=(short)f2bf(a.w);
  v[4]=(short)f2bf(b.x); v[5]=(short)f2bf(b.y); v[6]=(short)f2bf(b.z); v[7]=(short)f2bf(b.w);
  *(bf16x8*)(d + (size_t)i * 8) = v;
}

// ---------------- K1: upconv MFMA GEMM.  grid = 321*7, block (tile,ot) ----------------
// h[7n+ot][c] = x1[n] . Wup[ot*64+c] + bup,  A=x1b [NC][128], B=Wupb [448][128] (B^T form)
__global__ __launch_bounds__(256) void k_upconv(const u16* __restrict__ x1b,
                                                const u16* __restrict__ Wupb,
                                                const float* __restrict__ bup,
                                                u16* __restrict__ h){
  __shared__ __align__(16) unsigned char smem[52224];
  u16* As = (u16*)smem;               // [128][136] bf16
  u16* Bs = (u16*)(smem + 34816);     // [64][136]
  float* Cs = (float*)smem;           // [128][68] f32 (overlaps As after sync)
  const int t = threadIdx.x, l = t & 63, w = t >> 6;
  const int nn = t >> 1, half = t & 1;
  const int tile = blockIdx.x / 7, ot = blockIdx.x % 7;
  {
    int row = tile * 128 + nn; if (row >= NC) row = NC - 1;
    const int4* gp = (const int4*)(x1b + (size_t)row * 128 + half * 64);
#pragma unroll
    for (int u = 0; u < 8; ++u) *(int4*)(As + nn * 136 + half * 64 + u * 8) = gp[u];
  }
  {
    int o = t & 63, ci = t >> 6;
    const int4* gp = (const int4*)(Wupb + (size_t)(ot * 64 + o) * 128 + ci * 32);
#pragma unroll
    for (int u = 0; u < 4; ++u) *(int4*)(Bs + o * 136 + ci * 32 + u * 8) = gp[u];
  }
  float bias[4];
#pragma unroll
  for (int nt = 0; nt < 4; ++nt) bias[nt] = bup[ot * 64 + nt * 16 + (l & 15)];
  __syncthreads();
  f32x4 acc[2][4];
#pragma unroll
  for (int m = 0; m < 2; ++m)
#pragma unroll
    for (int nt = 0; nt < 4; ++nt) { acc[m][nt][0]=0.f; acc[m][nt][1]=0.f; acc[m][nt][2]=0.f; acc[m][nt][3]=0.f; }
  const u16* pA = As + (w * 32 + (l & 15)) * 136 + (l >> 4) * 8;
  const u16* pB = Bs + (l & 15) * 136 + (l >> 4) * 8;
#pragma unroll
  for (int kk = 0; kk < 4; ++kk) {
    bf16x8 a0 = *(const bf16x8*)(pA + kk * 32);
    bf16x8 a1 = *(const bf16x8*)(pA + 16 * 136 + kk * 32);
#pragma unroll
    for (int nt = 0; nt < 4; ++nt) {
      bf16x8 b = *(const bf16x8*)(pB + nt * 16 * 136 + kk * 32);
      acc[0][nt] = MFMA(a0, b, acc[0][nt]);
      acc[1][nt] = MFMA(a1, b, acc[1][nt]);
    }
  }
  __syncthreads();
#pragma unroll
  for (int m = 0; m < 2; ++m)
#pragma unroll
    for (int nt = 0; nt < 4; ++nt)
#pragma unroll
      for (int r = 0; r < 4; ++r) {
        int rl = w * 32 + m * 16 + (l >> 4) * 4 + r;
        Cs[rl * 68 + nt * 16 + (l & 15)] = acc[m][nt][r] + bias[nt];
      }
  __syncthreads();
  {
    int node = tile * 128 + nn;
    if (node < NC) {
      u16* dst = h + (size_t)(7 * node + ot) * 64 + half * 32;
      const float* cp = Cs + nn * 68 + half * 32;
#pragma unroll
      for (int u = 0; u < 4; ++u) {
        bf16x8 v;
#pragma unroll
        for (int e = 0; e < 8; ++e) v[e] = (short)f2bf(cp[u * 8 + e]);
        *(bf16x8*)(dst + u * 8) = v;
      }
    }
  }
}

// ---------------- K2: x = concat([x1u, x2],1) as bf16 ----------------
__global__ void k_build_x(const u16* __restrict__ h, const float* __restrict__ x2,
                          const int* __restrict__ topi, const int* __restrict__ downi,
                          u16* __restrict__ x){
  int gid = blockIdx.x * 256 + threadIdx.x;
  if (gid >= NF * 16) return;
  int n = gid >> 4, q = gid & 15;     // 8-channel chunk q of 16
  u16* dst = x + (size_t)n * 128 + q * 8;
  if (q >= 8) {
    const float4* sp = (const float4*)(x2 + (size_t)n * 64 + (q - 8) * 8);
    float4 a = sp[0], b = sp[1];
    bf16x8 v;
    v[0]=(short)f2bf(a.x); v[1]=(short)f2bf(a.y); v[2]=(short)f2bf(a.z); v[3]=(short)f2bf(a.w);
    v[4]=(short)f2bf(b.x); v[5]=(short)f2bf(b.y); v[6]=(short)f2bf(b.z); v[7]=(short)f2bf(b.w);
    *(bf16x8*)dst = v;
  } else if (n < NC) {
    int r = topi[n];
    *(int4*)dst = *(const int4*)(h + (size_t)r * 64 + q * 8);
  } else {
    int i = n - NC, hi = (q >= 4) ? 1 : 0;
    int r = downi[2 * i + hi];
    const u16* sp = h + (size_t)r * 64 + 16 * q - 64 * hi;
    bf16x8 v;
#pragma unroll
    for (int e = 0; e < 8; ++e)
      v[e] = (short)f2bf(0.5f * (bf2f(sp[2 * e]) + bf2f(sp[2 * e + 1])));
    *(bf16x8*)dst = v;
  }
}

// ---------------- K3: conv1 MFMA (gather K=896) + BN partials ----------------
__global__ __launch_bounds__(256) void k_conv1(const u16* __restrict__ xb,
                                               const int* __restrict__ neigh,
                                               const u16* __restrict__ W1b,
                                               const float* __restrict__ b1,
                                               u16* __restrict__ yb,
                                               float* __restrict__ psum,
                                               float* __restrict__ psq){
  __shared__ __align__(16) unsigned char smem[52224];
  u16* As = (u16*)smem;               // [128][136]
  u16* Bs = (u16*)(smem + 34816);     // [64][136]
  float* Cs = (float*)smem;           // [128][68]
  float* Ss = (float*)(smem + 34816); // [16][64]
  float* Qs = (float*)(smem + 34816 + 4096);
  const int t = threadIdx.x, l = t & 63, w = t >> 6;
  const int nn = t >> 1, half = t & 1;
  const int node_s = blockIdx.x * 128 + nn;
  f32x4 acc[2][4];
#pragma unroll
  for (int m = 0; m < 2; ++m)
#pragma unroll
    for (int nt = 0; nt < 4; ++nt) { acc[m][nt][0]=0.f; acc[m][nt][1]=0.f; acc[m][nt][2]=0.f; acc[m][nt][3]=0.f; }
  float bias[4];
#pragma unroll
  for (int nt = 0; nt < 4; ++nt) bias[nt] = b1[nt * 16 + (l & 15)];
  for (int j = 0; j < 7; ++j) {
    __syncthreads();
    {
      int r = (node_s < NF) ? neigh[7 * node_s + j] : 0;
      const int4* gp = (const int4*)(xb + (size_t)r * 128 + half * 64);
#pragma unroll
      for (int u = 0; u < 8; ++u) *(int4*)(As + nn * 136 + half * 64 + u * 8) = gp[u];
    }
    {
      int o = t & 63, ci = t >> 6;
      const int4* gp = (const int4*)(W1b + (size_t)o * 896 + j * 128 + ci * 32);
#pragma unroll
      for (int u = 0; u < 4; ++u) *(int4*)(Bs + o * 136 + ci * 32 + u * 8) = gp[u];
    }
    __syncthreads();
    const u16* pA = As + (w * 32 + (l & 15)) * 136 + (l >> 4) * 8;
    const u16* pB = Bs + (l & 15) * 136 + (l >> 4) * 8;
#pragma unroll
    for (int kk = 0; kk < 4; ++kk) {
      bf16x8 a0 = *(const bf16x8*)(pA + kk * 32);
      bf16x8 a1 = *(const bf16x8*)(pA + 16 * 136 + kk * 32);
#pragma unroll
      for (int nt = 0; nt < 4; ++nt) {
        bf16x8 b = *(const bf16x8*)(pB + nt * 16 * 136 + kk * 32);
        acc[0][nt] = MFMA(a0, b, acc[0][nt]);
        acc[1][nt] = MFMA(a1, b, acc[1][nt]);
      }
    }
  }
  __syncthreads();
  float s[4] = {0.f,0.f,0.f,0.f}, q[4] = {0.f,0.f,0.f,0.f};
#pragma unroll
  for (int m = 0; m < 2; ++m)
#pragma unroll
    for (int nt = 0; nt < 4; ++nt)
#pragma unroll
      for (int r = 0; r < 4; ++r) {
        int rl = w * 32 + m * 16 + (l >> 4) * 4 + r;
        float v = acc[m][nt][r] + bias[nt];
        Cs[rl * 68 + nt * 16 + (l & 15)] = v;
        if (blockIdx.x * 128 + rl < NF) { s[nt] += v; q[nt] += v * v; }
      }
#pragma unroll
  for (int nt = 0; nt < 4; ++nt) {
    int idx = (w * 4 + (l >> 4)) * 64 + nt * 16 + (l & 15);
    Ss[idx] = s[nt]; Qs[idx] = q[nt];
  }
  __syncthreads();
  if (node_s < NF) {
    u16* dst = yb + (size_t)node_s * 64 + half * 32;
    const float* cp = Cs + nn * 68 + half * 32;
#pragma unroll
    for (int u = 0; u < 4; ++u) {
      bf16x8 v;
#pragma unroll
      for (int e = 0; e < 8; ++e) v[e] = (short)f2bf(cp[u * 8 + e]);
      *(bf16x8*)(dst + u * 8) = v;
    }
  }
  if (t < 64) {
    float S = 0.f, Q = 0.f;
#pragma unroll
    for (int rr = 0; rr < 16; ++rr) { S += Ss[rr * 64 + t]; Q += Qs[rr * 64 + t]; }
    psum[blockIdx.x * 64 + t] = S;
    psq [blockIdx.x * 64 + t] = Q;
  }
}

// ---------------- K4: BN stats finalize ----------------
__global__ __launch_bounds__(256) void k_stats(const float* __restrict__ ps,
                                               const float* __restrict__ pq,
                                               int nblk,
                                               const float* __restrict__ g,
                                               const float* __restrict__ beta,
                                               float* __restrict__ st){
  __shared__ float sh[8][64];
  const int t = threadIdx.x, c = t & 63, r = t >> 6;
  float S = 0.f, Q = 0.f;
  for (int b = r; b < nblk; b += 4) { S += ps[b * 64 + c]; Q += pq[b * 64 + c]; }
  sh[r][c] = S; sh[4 + r][c] = Q;
  __syncthreads();
  if (t < 64) {
    float Ss = sh[0][t] + sh[1][t] + sh[2][t] + sh[3][t];
    float Qs = sh[4][t] + sh[5][t] + sh[6][t] + sh[7][t];
    float mean = Ss * (1.f / (float)NF);
    float var  = Qs * (1.f / (float)NF) - mean * mean;
    var = var < 0.f ? 0.f : var;
    float scale = g[t] * rsqrtf(var + EPSV);
    st[t] = scale;
    st[64 + t] = beta[t] - mean * scale;
  }
}

// ---------------- K5: conv2 MFMA (gather K=448, BN1+lrelu in staging) ----------------
__global__ __launch_bounds__(256) void k_conv2(const u16* __restrict__ yb,
                                               const int* __restrict__ neigh,
                                               const u16* __restrict__ W2b,
                                               const float* __restrict__ b2,
                                               const float* __restrict__ st1,
                                               float* __restrict__ op,
                                               float* __restrict__ psum,
                                               float* __restrict__ psq){
  __shared__ __align__(16) unsigned char smem[43520];
  u16* As = (u16*)smem;               // [128][72]
  u16* Bs = (u16*)(smem + 18432);     // [64][72]
  float* Cs = (float*)smem;           // [128][68]
  float* Ss = (float*)(smem + 34816);
  float* Qs = (float*)(smem + 34816 + 4096);
  float* Sst = (float*)(smem + 43008); // st1 cache [128]
  const int t = threadIdx.x, l = t & 63, w = t >> 6;
  const int nn = t >> 1, half = t & 1;
  const int node_s = blockIdx.x * 128 + nn;
  if (t < 128) Sst[t] = st1[t];
  f32x4 acc[2][4];
#pragma unroll
  for (int m = 0; m < 2; ++m)
#pragma unroll
    for (int nt = 0; nt < 4; ++nt) { acc[m][nt][0]=0.f; acc[m][nt][1]=0.f; acc[m][nt][2]=0.f; acc[m][nt][3]=0.f; }
  float bias[4];
#pragma unroll
  for (int nt = 0; nt < 4; ++nt) bias[nt] = b2[nt * 16 + (l & 15)];
  for (int j = 0; j < 7; ++j) {
    __syncthreads();
    {
      int r = (node_s < NF) ? neigh[7 * node_s + j] : 0;
      const int4* gp = (const int4*)(yb + (size_t)r * 64 + half * 32);
#pragma unroll
      for (int u = 0; u < 4; ++u) {
        int c8 = half * 4 + u;
        int4 raw = gp[u];
        u16* pr = (u16*)&raw;
        bf16x8 v;
#pragma unroll
        for (int e = 0; e < 8; ++e) {
          float f = bf2f(pr[e]) * Sst[c8 * 8 + e] + Sst[64 + c8 * 8 + e];
          v[e] = (short)f2bf(lrelu(f));
        }
        *(bf16x8*)(As + nn * 72 + c8 * 8) = v;
      }
    }
    {
      int o = t & 63, ci = t >> 6;
      const int4* gp = (const int4*)(W2b + (size_t)o * 448 + j * 64 + ci * 16);
#pragma unroll
      for (int u = 0; u < 2; ++u) *(int4*)(Bs + o * 72 + ci * 16 + u * 8) = gp[u];
    }
    __syncthreads();
    const u16* pA = As + (w * 32 + (l & 15)) * 72 + (l >> 4) * 8;
    const u16* pB = Bs + (l & 15) * 72 + (l >> 4) * 8;
#pragma unroll
    for (int kk = 0; kk < 2; ++kk) {
      bf16x8 a0 = *(const bf16x8*)(pA + kk * 32);
      bf16x8 a1 = *(const bf16x8*)(pA + 16 * 72 + kk * 32);
#pragma unroll
      for (int nt = 0; nt < 4; ++nt) {
        bf16x8 b = *(const bf16x8*)(pB + nt * 16 * 72 + kk * 32);
        acc[0][nt] = MFMA(a0, b, acc[0][nt]);
        acc[1][nt] = MFMA(a1, b, acc[1][nt]);
      }
    }
  }
  __syncthreads();
  float s[4] = {0.f,0.f,0.f,0.f}, q[4] = {0.f,0.f,0.f,0.f};
#pragma unroll
  for (int m = 0; m < 2; ++m)
#pragma unroll
    for (int nt = 0; nt < 4; ++nt)
#pragma unroll
      for (int r = 0; r < 4; ++r) {
        int rl = w * 32 + m * 16 + (l >> 4) * 4 + r;
        float v = acc[m][nt][r] + bias[nt];
        Cs[rl * 68 + nt * 16 + (l & 15)] = v;
        if (blockIdx.x * 128 + rl < NF) { s[nt] += v; q[nt] += v * v; }
      }
#pragma unroll
  for (int nt = 0; nt < 4; ++nt) {
    int idx = (w * 4 + (l >> 4)) * 64 + nt * 16 + (l & 15);
    Ss[idx] = s[nt]; Qs[idx] = q[nt];
  }
  __syncthreads();
  if (node_s < NF) {
    float4* dst = (float4*)(op + (size_t)node_s * 64 + half * 32);
    const float* cp = Cs + nn * 68 + half * 32;
#pragma unroll
    for (int u = 0; u < 8; ++u) dst[u] = *(const float4*)(cp + u * 4);
  }
  if (t < 64) {
    float S = 0.f, Q = 0.f;
#pragma unroll
    for (int rr = 0; rr < 16; ++rr) { S += Ss[rr * 64 + t]; Q += Qs[rr * 64 + t]; }
    psum[blockIdx.x * 64 + t] = S;
    psq [blockIdx.x * 64 + t] = Q;
  }
}

// ---------------- K6: apply BN2 + leaky ----------------
__global__ void k_apply(const float* __restrict__ op, const float* __restrict__ st2,
                        float* __restrict__ out){
  int gid = blockIdx.x * blockDim.x + threadIdx.x;
  if (gid >= NF * 16) return;
  int q = gid & 15;
  float4 v  = *(const float4*)(op + (size_t)gid * 4);
  float4 s  = *(const float4*)(st2 + q * 4);
  float4 sh = *(const float4*)(st2 + 64 + q * 4);
  float4 w2;
  w2.x = lrelu(v.x * s.x + sh.x);
  w2.y = lrelu(v.y * s.y + sh.y);
  w2.z = lrelu(v.z * s.z + sh.z);
  w2.w = lrelu(v.w * s.w + sh.w);
  *(float4*)(out + (size_t)gid * 4) = w2;
}

extern "C" void kernel_launch(void* const* d_in, const int* in_sizes, int n_in,
                              void* d_out, int out_size, void* d_ws, size_t ws_size,
                              hipStream_t stream) {
  (void)in_sizes; (void)n_in; (void)out_size; (void)ws_size;
  const float* x1   = (const float*)d_in[0];
  const float* x2   = (const float*)d_in[1];
  const int*   topi = (const int*)d_in[2];
  const int*   downi= (const int*)d_in[3];
  const int*   neigh= (const int*)d_in[4];
  const float* Wup  = (const float*)d_in[5];
  const float* bup  = (const float*)d_in[6];
  const float* W1   = (const float*)d_in[7];
  const float* b1   = (const float*)d_in[8];
  const float* g1   = (const float*)d_in[9];
  const float* be1  = (const float*)d_in[10];
  const float* W2   = (const float*)d_in[11];
  const float* b2   = (const float*)d_in[12];
  const float* g2   = (const float*)d_in[13];
  const float* be2  = (const float*)d_in[14];
  float* out = (float*)d_out;

  char* ws = (char*)d_ws;
  // layout (op f32 aliases h+x head; x dead before conv2 writes op)
  u16*   h    = (u16*)(ws);                          // 7NC x 64 bf16 = 36,701,952 B
  float* op   = (float*)(ws);                        // NF x 64 f32  = 41,943,552 B
  u16*   x    = (u16*)(ws + 36701952ull);            // NF x 128 bf16 = 41,943,552 B
  u16*   y    = (u16*)(ws + 78645504ull);            // NF x 64 bf16  = 20,971,776 B
  u16*   x1b  = (u16*)(ws + 99617280ull);            // NC x 128 bf16 = 10,486,272 B
  u16*   Wupb = (u16*)(ws + 110103552ull);           // 448x128 bf16  = 114,688 B
  u16*   W1b  = (u16*)(ws + 110218240ull);           // 64x896 bf16   = 114,688 B
  u16*   W2b  = (u16*)(ws + 110332928ull);           // 64x448 bf16   = 57,344 B
  float* p1s  = (float*)(ws + 110390272ull);         // NBLK*64 f32 = 327,936 B each
  float* p1q  = (float*)(ws + 110718208ull);
  float* p2s  = (float*)(ws + 111046144ull);
  float* p2q  = (float*)(ws + 111374080ull);
  float* st1  = (float*)(ws + 111702016ull);
  float* st2  = (float*)(ws + 111702528ull);

  k_f2bf<<<2561, 256, 0, stream>>>(x1, x1b, 655392);
  k_f2bf<<<28, 256, 0, stream>>>(Wup, Wupb, 7168);
  k_f2bf<<<28, 256, 0, stream>>>(W1, W1b, 7168);
  k_f2bf<<<14, 256, 0, stream>>>(W2, W2b, 3584);

  k_upconv <<<321 * 7, 256, 0, stream>>>(x1b, Wupb, bup, h);
  k_build_x<<<(NF * 16 + 255) / 256, 256, 0, stream>>>(h, x2, topi, downi, x);
  k_conv1  <<<NBLK, 256, 0, stream>>>(x, neigh, W1b, b1, y, p1s, p1q);
  k_stats  <<<1, 256, 0, stream>>>(p1s, p1q, NBLK, g1, be1, st1);
  k_conv2  <<<NBLK, 256, 0, stream>>>(y, neigh, W2b, b2, st1, op, p2s, p2q);
  k_stats  <<<1, 256, 0, stream>>>(p2s, p2q, NBLK, g2, be2, st2);
  k_apply  <<<(NF * 16 + 255) / 256, 256, 0, stream>>>(op, st2, out);
}

// Round 4
// 203.785 us; speedup vs baseline: 4.7054x; 1.7825x over previous
//
#include <hip/hip_runtime.h>
#include <math.h>

#define NC 40962
#define NF 163842
#define EPSV 1e-5f
#define LSLOPE 0.2f
#define NBLK 1281           // ceil(NF/128)

typedef __attribute__((ext_vector_type(8))) short bf16x8;
typedef __attribute__((ext_vector_type(4))) float f32x4;
typedef unsigned short u16;

#define MFMA(a,b,c) __builtin_amdgcn_mfma_f32_16x16x32_bf16(a,b,c,0,0,0)

__device__ __forceinline__ u16 f2bf(float f){
  unsigned u = __float_as_uint(f);
  u += 0x7fffu + ((u >> 16) & 1u);
  return (u16)(u >> 16);
}
__device__ __forceinline__ float bf2f(u16 h){ return __uint_as_float(((unsigned)h) << 16); }
__device__ __forceinline__ float lrelu(float v){ return v > 0.f ? v : LSLOPE * v; }

// ---------------- convert f32 -> bf16, 8 elems/thread ----------------
__global__ void k_f2bf(const float* __restrict__ s, u16* __restrict__ d, int n8){
  int i = blockIdx.x * 256 + threadIdx.x;
  if (i >= n8) return;
  const float4* sp = (const float4*)(s + (size_t)i * 8);
  float4 a = sp[0], b = sp[1];
  bf16x8 v;
  v[0]=(short)f2bf(a.x); v[1]=(short)f2bf(a.y); v[2]=(short)f2bf(a.z); v[3]=(short)f2bf(a.w);
  v[4]=(short)f2bf(b.x); v[5]=(short)f2bf(b.y); v[6]=(short)f2bf(b.z); v[7]=(short)f2bf(b.w);
  *(bf16x8*)(d + (size_t)i * 8) = v;
}

// ---------------- K1: upconv MFMA GEMM.  grid = 321*7, block (tile,ot) ----------------
__global__ __launch_bounds__(256) void k_upconv(const u16* __restrict__ x1b,
                                                const u16* __restrict__ Wupb,
                                                const float* __restrict__ bup,
                                                u16* __restrict__ h){
  __shared__ __align__(16) unsigned char smem[52224];
  u16* As = (u16*)smem;               // [128][136] bf16
  u16* Bs = (u16*)(smem + 34816);     // [64][136]
  float* Cs = (float*)smem;           // [128][68] f32 (overlaps As after sync)
  const int t = threadIdx.x, l = t & 63, w = t >> 6;
  const int nn = t >> 1, half = t & 1;
  const int tile = blockIdx.x / 7, ot = blockIdx.x % 7;
  {
    int row = tile * 128 + nn; if (row >= NC) row = NC - 1;
    const int4* gp = (const int4*)(x1b + (size_t)row * 128 + half * 64);
#pragma unroll
    for (int u = 0; u < 8; ++u) *(int4*)(As + nn * 136 + half * 64 + u * 8) = gp[u];
  }
  {
    int o = t & 63, ci = t >> 6;
    const int4* gp = (const int4*)(Wupb + (size_t)(ot * 64 + o) * 128 + ci * 32);
#pragma unroll
    for (int u = 0; u < 4; ++u) *(int4*)(Bs + o * 136 + ci * 32 + u * 8) = gp[u];
  }
  float bias[4];
#pragma unroll
  for (int nt = 0; nt < 4; ++nt) bias[nt] = bup[ot * 64 + nt * 16 + (l & 15)];
  __syncthreads();
  f32x4 acc[2][4];
#pragma unroll
  for (int m = 0; m < 2; ++m)
#pragma unroll
    for (int nt = 0; nt < 4; ++nt) { acc[m][nt][0]=0.f; acc[m][nt][1]=0.f; acc[m][nt][2]=0.f; acc[m][nt][3]=0.f; }
  const u16* pA = As + (w * 32 + (l & 15)) * 136 + (l >> 4) * 8;
  const u16* pB = Bs + (l & 15) * 136 + (l >> 4) * 8;
#pragma unroll
  for (int kk = 0; kk < 4; ++kk) {
    bf16x8 a0 = *(const bf16x8*)(pA + kk * 32);
    bf16x8 a1 = *(const bf16x8*)(pA + 16 * 136 + kk * 32);
#pragma unroll
    for (int nt = 0; nt < 4; ++nt) {
      bf16x8 b = *(const bf16x8*)(pB + nt * 16 * 136 + kk * 32);
      acc[0][nt] = MFMA(a0, b, acc[0][nt]);
      acc[1][nt] = MFMA(a1, b, acc[1][nt]);
    }
  }
  __syncthreads();
#pragma unroll
  for (int m = 0; m < 2; ++m)
#pragma unroll
    for (int nt = 0; nt < 4; ++nt)
#pragma unroll
      for (int r = 0; r < 4; ++r) {
        int rl = w * 32 + m * 16 + (l >> 4) * 4 + r;
        Cs[rl * 68 + nt * 16 + (l & 15)] = acc[m][nt][r] + bias[nt];
      }
  __syncthreads();
  {
    int node = tile * 128 + nn;
    if (node < NC) {
      u16* dst = h + (size_t)(7 * node + ot) * 64 + half * 32;
      const float* cp = Cs + nn * 68 + half * 32;
#pragma unroll
      for (int u = 0; u < 4; ++u) {
        bf16x8 v;
#pragma unroll
        for (int e = 0; e < 8; ++e) v[e] = (short)f2bf(cp[u * 8 + e]);
        *(bf16x8*)(dst + u * 8) = v;
      }
    }
  }
}

// ---------------- K2: x = concat([x1u, x2],1) as bf16 ----------------
__global__ void k_build_x(const u16* __restrict__ h, const float* __restrict__ x2,
                          const int* __restrict__ topi, const int* __restrict__ downi,
                          u16* __restrict__ x){
  int gid = blockIdx.x * 256 + threadIdx.x;
  if (gid >= NF * 16) return;
  int n = gid >> 4, q = gid & 15;     // 8-channel chunk q of 16
  u16* dst = x + (size_t)n * 128 + q * 8;
  if (q >= 8) {
    const float4* sp = (const float4*)(x2 + (size_t)n * 64 + (q - 8) * 8);
    float4 a = sp[0], b = sp[1];
    bf16x8 v;
    v[0]=(short)f2bf(a.x); v[1]=(short)f2bf(a.y); v[2]=(short)f2bf(a.z); v[3]=(short)f2bf(a.w);
    v[4]=(short)f2bf(b.x); v[5]=(short)f2bf(b.y); v[6]=(short)f2bf(b.z); v[7]=(short)f2bf(b.w);
    *(bf16x8*)dst = v;
  } else if (n < NC) {
    int r = topi[n];
    *(int4*)dst = *(const int4*)(h + (size_t)r * 64 + q * 8);
  } else {
    int i = n - NC, hi = (q >= 4) ? 1 : 0;
    int r = downi[2 * i + hi];
    const u16* sp = h + (size_t)r * 64 + 16 * q - 64 * hi;
    bf16x8 v;
#pragma unroll
    for (int e = 0; e < 8; ++e)
      v[e] = (short)f2bf(0.5f * (bf2f(sp[2 * e]) + bf2f(sp[2 * e + 1])));
    *(bf16x8*)dst = v;
  }
}

// ---------------- K3: conv1 MFMA (gather K=896) + BN partials ----------------
__global__ __launch_bounds__(256) void k_conv1(const u16* __restrict__ xb,
                                               const int* __restrict__ neigh,
                                               const u16* __restrict__ W1b,
                                               const float* __restrict__ b1,
                                               u16* __restrict__ yb,
                                               float* __restrict__ psum,
                                               float* __restrict__ psq){
  __shared__ __align__(16) unsigned char smem[52224];
  u16* As = (u16*)smem;               // [128][136]
  u16* Bs = (u16*)(smem + 34816);     // [64][136]
  float* Cs = (float*)smem;           // [128][68]
  float* Ss = (float*)(smem + 34816); // [16][64]
  float* Qs = (float*)(smem + 34816 + 4096);
  const int t = threadIdx.x, l = t & 63, w = t >> 6;
  const int nn = t >> 1, half = t & 1;
  const int node_s = blockIdx.x * 128 + nn;
  f32x4 acc[2][4];
#pragma unroll
  for (int m = 0; m < 2; ++m)
#pragma unroll
    for (int nt = 0; nt < 4; ++nt) { acc[m][nt][0]=0.f; acc[m][nt][1]=0.f; acc[m][nt][2]=0.f; acc[m][nt][3]=0.f; }
  float bias[4];
#pragma unroll
  for (int nt = 0; nt < 4; ++nt) bias[nt] = b1[nt * 16 + (l & 15)];
  for (int j = 0; j < 7; ++j) {
    __syncthreads();
    {
      int r = (node_s < NF) ? neigh[7 * node_s + j] : 0;
      const int4* gp = (const int4*)(xb + (size_t)r * 128 + half * 64);
#pragma unroll
      for (int u = 0; u < 8; ++u) *(int4*)(As + nn * 136 + half * 64 + u * 8) = gp[u];
    }
    {
      int o = t & 63, ci = t >> 6;
      const int4* gp = (const int4*)(W1b + (size_t)o * 896 + j * 128 + ci * 32);
#pragma unroll
      for (int u = 0; u < 4; ++u) *(int4*)(Bs + o * 136 + ci * 32 + u * 8) = gp[u];
    }
    __syncthreads();
    const u16* pA = As + (w * 32 + (l & 15)) * 136 + (l >> 4) * 8;
    const u16* pB = Bs + (l & 15) * 136 + (l >> 4) * 8;
#pragma unroll
    for (int kk = 0; kk < 4; ++kk) {
      bf16x8 a0 = *(const bf16x8*)(pA + kk * 32);
      bf16x8 a1 = *(const bf16x8*)(pA + 16 * 136 + kk * 32);
#pragma unroll
      for (int nt = 0; nt < 4; ++nt) {
        bf16x8 b = *(const bf16x8*)(pB + nt * 16 * 136 + kk * 32);
        acc[0][nt] = MFMA(a0, b, acc[0][nt]);
        acc[1][nt] = MFMA(a1, b, acc[1][nt]);
      }
    }
  }
  __syncthreads();
  float s[4] = {0.f,0.f,0.f,0.f}, q[4] = {0.f,0.f,0.f,0.f};
#pragma unroll
  for (int m = 0; m < 2; ++m)
#pragma unroll
    for (int nt = 0; nt < 4; ++nt)
#pragma unroll
      for (int r = 0; r < 4; ++r) {
        int rl = w * 32 + m * 16 + (l >> 4) * 4 + r;
        float v = acc[m][nt][r] + bias[nt];
        Cs[rl * 68 + nt * 16 + (l & 15)] = v;
        if (blockIdx.x * 128 + rl < NF) { s[nt] += v; q[nt] += v * v; }
      }
#pragma unroll
  for (int nt = 0; nt < 4; ++nt) {
    int idx = (w * 4 + (l >> 4)) * 64 + nt * 16 + (l & 15);
    Ss[idx] = s[nt]; Qs[idx] = q[nt];
  }
  __syncthreads();
  if (node_s < NF) {
    u16* dst = yb + (size_t)node_s * 64 + half * 32;
    const float* cp = Cs + nn * 68 + half * 32;
#pragma unroll
    for (int u = 0; u < 4; ++u) {
      bf16x8 v;
#pragma unroll
      for (int e = 0; e < 8; ++e) v[e] = (short)f2bf(cp[u * 8 + e]);
      *(bf16x8*)(dst + u * 8) = v;
    }
  }
  if (t < 64) {
    float S = 0.f, Q = 0.f;
#pragma unroll
    for (int rr = 0; rr < 16; ++rr) { S += Ss[rr * 64 + t]; Q += Qs[rr * 64 + t]; }
    psum[blockIdx.x * 64 + t] = S;
    psq [blockIdx.x * 64 + t] = Q;
  }
}

// ---------------- K4a: BN partial tree-reduce  [nblk][64] -> [32][64] ----------------
__global__ __launch_bounds__(256) void k_statsA(const float* __restrict__ ps,
                                                const float* __restrict__ pq,
                                                int nblk,
                                                float* __restrict__ os,
                                                float* __restrict__ oq){
  __shared__ float sh[8][64];
  const int t = threadIdx.x, c = t & 63, r = t >> 6;
  float S = 0.f, Q = 0.f;
  for (int b = blockIdx.x * 4 + r; b < nblk; b += 128) { S += ps[b * 64 + c]; Q += pq[b * 64 + c]; }
  sh[r][c] = S; sh[4 + r][c] = Q;
  __syncthreads();
  if (t < 64) {
    os[blockIdx.x * 64 + t] = sh[0][t] + sh[1][t] + sh[2][t] + sh[3][t];
    oq[blockIdx.x * 64 + t] = sh[4][t] + sh[5][t] + sh[6][t] + sh[7][t];
  }
}

// ---------------- K4b: BN stats finalize (reads 32 rows) ----------------
__global__ __launch_bounds__(256) void k_stats(const float* __restrict__ ps,
                                               const float* __restrict__ pq,
                                               int nblk,
                                               const float* __restrict__ g,
                                               const float* __restrict__ beta,
                                               float* __restrict__ st){
  __shared__ float sh[8][64];
  const int t = threadIdx.x, c = t & 63, r = t >> 6;
  float S = 0.f, Q = 0.f;
  for (int b = r; b < nblk; b += 4) { S += ps[b * 64 + c]; Q += pq[b * 64 + c]; }
  sh[r][c] = S; sh[4 + r][c] = Q;
  __syncthreads();
  if (t < 64) {
    float Ss = sh[0][t] + sh[1][t] + sh[2][t] + sh[3][t];
    float Qs = sh[4][t] + sh[5][t] + sh[6][t] + sh[7][t];
    float mean = Ss * (1.f / (float)NF);
    float var  = Qs * (1.f / (float)NF) - mean * mean;
    var = var < 0.f ? 0.f : var;
    float scale = g[t] * rsqrtf(var + EPSV);
    st[t] = scale;
    st[64 + t] = beta[t] - mean * scale;
  }
}

// ---------------- K5: conv2 MFMA (gather K=448, BN1+lrelu in staging) ----------------
__global__ __launch_bounds__(256) void k_conv2(const u16* __restrict__ yb,
                                               const int* __restrict__ neigh,
                                               const u16* __restrict__ W2b,
                                               const float* __restrict__ b2,
                                               const float* __restrict__ st1,
                                               float* __restrict__ op,
                                               float* __restrict__ psum,
                                               float* __restrict__ psq){
  __shared__ __align__(16) unsigned char smem[43520];
  u16* As = (u16*)smem;               // [128][72]
  u16* Bs = (u16*)(smem + 18432);     // [64][72]
  float* Cs = (float*)smem;           // [128][68]
  float* Ss = (float*)(smem + 34816);
  float* Qs = (float*)(smem + 34816 + 4096);
  float* Sst = (float*)(smem + 43008); // st1 cache [128]
  const int t = threadIdx.x, l = t & 63, w = t >> 6;
  const int nn = t >> 1, half = t & 1;
  const int node_s = blockIdx.x * 128 + nn;
  if (t < 128) Sst[t] = st1[t];
  f32x4 acc[2][4];
#pragma unroll
  for (int m = 0; m < 2; ++m)
#pragma unroll
    for (int nt = 0; nt < 4; ++nt) { acc[m][nt][0]=0.f; acc[m][nt][1]=0.f; acc[m][nt][2]=0.f; acc[m][nt][3]=0.f; }
  float bias[4];
#pragma unroll
  for (int nt = 0; nt < 4; ++nt) bias[nt] = b2[nt * 16 + (l & 15)];
  for (int j = 0; j < 7; ++j) {
    __syncthreads();
    {
      int r = (node_s < NF) ? neigh[7 * node_s + j] : 0;
      const int4* gp = (const int4*)(yb + (size_t)r * 64 + half * 32);
#pragma unroll
      for (int u = 0; u < 4; ++u) {
        int c8 = half * 4 + u;
        int4 raw = gp[u];
        u16* pr = (u16*)&raw;
        bf16x8 v;
#pragma unroll
        for (int e = 0; e < 8; ++e) {
          float f = bf2f(pr[e]) * Sst[c8 * 8 + e] + Sst[64 + c8 * 8 + e];
          v[e] = (short)f2bf(lrelu(f));
        }
        *(bf16x8*)(As + nn * 72 + c8 * 8) = v;
      }
    }
    {
      int o = t & 63, ci = t >> 6;
      const int4* gp = (const int4*)(W2b + (size_t)o * 448 + j * 64 + ci * 16);
#pragma unroll
      for (int u = 0; u < 2; ++u) *(int4*)(Bs + o * 72 + ci * 16 + u * 8) = gp[u];
    }
    __syncthreads();
    const u16* pA = As + (w * 32 + (l & 15)) * 72 + (l >> 4) * 8;
    const u16* pB = Bs + (l & 15) * 72 + (l >> 4) * 8;
#pragma unroll
    for (int kk = 0; kk < 2; ++kk) {
      bf16x8 a0 = *(const bf16x8*)(pA + kk * 32);
      bf16x8 a1 = *(const bf16x8*)(pA + 16 * 72 + kk * 32);
#pragma unroll
      for (int nt = 0; nt < 4; ++nt) {
        bf16x8 b = *(const bf16x8*)(pB + nt * 16 * 72 + kk * 32);
        acc[0][nt] = MFMA(a0, b, acc[0][nt]);
        acc[1][nt] = MFMA(a1, b, acc[1][nt]);
      }
    }
  }
  __syncthreads();
  float s[4] = {0.f,0.f,0.f,0.f}, q[4] = {0.f,0.f,0.f,0.f};
#pragma unroll
  for (int m = 0; m < 2; ++m)
#pragma unroll
    for (int nt = 0; nt < 4; ++nt)
#pragma unroll
      for (int r = 0; r < 4; ++r) {
        int rl = w * 32 + m * 16 + (l >> 4) * 4 + r;
        float v = acc[m][nt][r] + bias[nt];
        Cs[rl * 68 + nt * 16 + (l & 15)] = v;
        if (blockIdx.x * 128 + rl < NF) { s[nt] += v; q[nt] += v * v; }
      }
#pragma unroll
  for (int nt = 0; nt < 4; ++nt) {
    int idx = (w * 4 + (l >> 4)) * 64 + nt * 16 + (l & 15);
    Ss[idx] = s[nt]; Qs[idx] = q[nt];
  }
  __syncthreads();
  if (node_s < NF) {
    float4* dst = (float4*)(op + (size_t)node_s * 64 + half * 32);
    const float* cp = Cs + nn * 68 + half * 32;
#pragma unroll
    for (int u = 0; u < 8; ++u) dst[u] = *(const float4*)(cp + u * 4);
  }
  if (t < 64) {
    float S = 0.f, Q = 0.f;
#pragma unroll
    for (int rr = 0; rr < 16; ++rr) { S += Ss[rr * 64 + t]; Q += Qs[rr * 64 + t]; }
    psum[blockIdx.x * 64 + t] = S;
    psq [blockIdx.x * 64 + t] = Q;
  }
}

// ---------------- K6: apply BN2 + leaky ----------------
__global__ void k_apply(const float* __restrict__ op, const float* __restrict__ st2,
                        float* __restrict__ out){
  int gid = blockIdx.x * blockDim.x + threadIdx.x;
  if (gid >= NF * 16) return;
  int q = gid & 15;
  float4 v  = *(const float4*)(op + (size_t)gid * 4);
  float4 s  = *(const float4*)(st2 + q * 4);
  float4 sh = *(const float4*)(st2 + 64 + q * 4);
  float4 w2;
  w2.x = lrelu(v.x * s.x + sh.x);
  w2.y = lrelu(v.y * s.y + sh.y);
  w2.z = lrelu(v.z * s.z + sh.z);
  w2.w = lrelu(v.w * s.w + sh.w);
  *(float4*)(out + (size_t)gid * 4) = w2;
}

extern "C" void kernel_launch(void* const* d_in, const int* in_sizes, int n_in,
                              void* d_out, int out_size, void* d_ws, size_t ws_size,
                              hipStream_t stream) {
  (void)in_sizes; (void)n_in; (void)out_size; (void)ws_size;
  const float* x1   = (const float*)d_in[0];
  const float* x2   = (const float*)d_in[1];
  const int*   topi = (const int*)d_in[2];
  const int*   downi= (const int*)d_in[3];
  const int*   neigh= (const int*)d_in[4];
  const float* Wup  = (const float*)d_in[5];
  const float* bup  = (const float*)d_in[6];
  const float* W1   = (const float*)d_in[7];
  const float* b1   = (const float*)d_in[8];
  const float* g1   = (const float*)d_in[9];
  const float* be1  = (const float*)d_in[10];
  const float* W2   = (const float*)d_in[11];
  const float* b2   = (const float*)d_in[12];
  const float* g2   = (const float*)d_in[13];
  const float* be2  = (const float*)d_in[14];
  float* out = (float*)d_out;

  char* ws = (char*)d_ws;
  u16*   h    = (u16*)(ws);                          // 7NC x 64 bf16 = 36,701,952 B
  float* op   = (float*)(ws);                        // NF x 64 f32  = 41,943,552 B (aliases h; h dead)
  u16*   x    = (u16*)(ws + 36701952ull);            // NF x 128 bf16 = 41,943,552 B
  u16*   y    = (u16*)(ws + 78645504ull);            // NF x 64 bf16  = 20,971,776 B
  u16*   x1b  = (u16*)(ws + 99617280ull);            // NC x 128 bf16 = 10,486,272 B
  u16*   Wupb = (u16*)(ws + 110103552ull);           // 448x128 bf16
  u16*   W1b  = (u16*)(ws + 110218240ull);           // 64x896 bf16
  u16*   W2b  = (u16*)(ws + 110332928ull);           // 64x448 bf16
  float* p1s  = (float*)(ws + 110390272ull);         // NBLK*64 f32 = 327,936 B each
  float* p1q  = (float*)(ws + 110718208ull);
  float* p2s  = (float*)(ws + 111046144ull);
  float* p2q  = (float*)(ws + 111374080ull);
  float* st1  = (float*)(ws + 111702016ull);
  float* st2  = (float*)(ws + 111702528ull);
  float* r1s  = (float*)(ws + 111703040ull);         // [32][64] f32 = 8192 B each
  float* r1q  = (float*)(ws + 111711232ull);
  float* r2s  = (float*)(ws + 111719424ull);
  float* r2q  = (float*)(ws + 111727616ull);

  k_f2bf<<<2561, 256, 0, stream>>>(x1, x1b, 655392);
  k_f2bf<<<28, 256, 0, stream>>>(Wup, Wupb, 7168);
  k_f2bf<<<28, 256, 0, stream>>>(W1, W1b, 7168);
  k_f2bf<<<14, 256, 0, stream>>>(W2, W2b, 3584);

  k_upconv <<<321 * 7, 256, 0, stream>>>(x1b, Wupb, bup, h);
  k_build_x<<<(NF * 16 + 255) / 256, 256, 0, stream>>>(h, x2, topi, downi, x);
  k_conv1  <<<NBLK, 256, 0, stream>>>(x, neigh, W1b, b1, y, p1s, p1q);
  k_statsA <<<32, 256, 0, stream>>>(p1s, p1q, NBLK, r1s, r1q);
  k_stats  <<<1, 256, 0, stream>>>(r1s, r1q, 32, g1, be1, st1);
  k_conv2  <<<NBLK, 256, 0, stream>>>(y, neigh, W2b, b2, st1, op, p2s, p2q);
  k_statsA <<<32, 256, 0, stream>>>(p2s, p2q, NBLK, r2s, r2q);
  k_stats  <<<1, 256, 0, stream>>>(r2s, r2q, 32, g2, be2, st2);
  k_apply  <<<(NF * 16 + 255) / 256, 256, 0, stream>>>(op, st2, out);
}